// Round 1
// baseline (267.110 us; speedup 1.0000x reference)
//
#include <hip/hip_runtime.h>

#define NDIM 31
#define IMG 256
#define NPIX (IMG * IMG)

// fast reciprocal: v_rcp_f32, ~1 ulp — far inside the 2% validation threshold
__device__ __forceinline__ float rcpf(float x) { return __builtin_amdgcn_rcpf(x); }

// broadcast lane s (0..31) within each 32-lane half of the wave.
// addr_base = (lane & 32) << 2 precomputed, so each call is 1 v_add + 1 ds_bpermute.
__device__ __forceinline__ float bcast_half(float v, int s, int addr_base) {
    return __int_as_float(
        __builtin_amdgcn_ds_bpermute(addr_base + (s << 2), __float_as_int(v)));
}

// 32-point Walsh-Hadamard transform across each 32-lane half:
// result at lane f = sum_l v_l * (-1)^popcount(l & f)
__device__ __forceinline__ float wht32(float v, int lane) {
#pragma unroll
    for (int m = 1; m < 32; m <<= 1) {
        float o = __shfl_xor(v, m);   // m < 32 => stays within the 32-lane half
        v = (lane & m) ? (o - v) : (v + o);
    }
    return v;
}

__global__ __launch_bounds__(256) void solver_kernel(
    const float* __restrict__ xg,   // time_points, (H,W,31,1) flat
    const float* __restrict__ kg,   // pixels
    const float* __restrict__ tg,   // scalar t
    float* __restrict__ out)        // (H,W) flat
{
    const int tid = blockIdx.x * 256 + threadIdx.x;
    const int pix = tid >> 5;                 // one 32-lane half-wave per pixel
    if (pix >= NPIX) return;
    const int lane = threadIdx.x & 63;
    const int l = lane & 31;                  // index within half; element = l-1
    const int bbase = (lane & 32) << 2;       // bpermute base for this half

    const float t = tg[0];

    // Load x, k for element l-1 (lane 0 is the zero-pad slot of the WHT)
    float x = 1.0f, k = 0.0f;
    if (l >= 1) {
        const int base = pix * NDIM + (l - 1);
        x = xg[base];
        k = kg[base];
    }

    // ---- rate = S x via WHT: rate[d] = 0.5*(xh[0] - xh[d+1]) (at lane d+1) ----
    float xt = (l >= 1) ? x : 0.0f;
    float xh = wht32(xt, lane);
    float xh0 = bcast_half(xh, 0, bbase);
    float rate = 0.5f * (xh0 - xh);

    float inv_rate = rcpf(rate);
    if (l == 0) inv_rate = 0.0f;              // rate==0 at pad slot; neutralize

    // v such that J = -(S^T v) - 1/x
    float v = t * (k * inv_rate - 1.0f) + inv_rate;
    float w = (t * k + 1.0f) * inv_rate * inv_rate;
    if (l == 0) { v = 0.0f; w = 0.0f; }       // zero-pad slot

    // ---- J ----
    float vh = wht32(v, lane);
    float vh0 = bcast_half(vh, 0, bbase);
    float invx = rcpf(x);
    float b = -0.5f * (vh0 - vh) - invx;      // J_{l-1} at lane l (lane0 unused)

    // ---- H = S diag(w) S^T + diag(1/x^2) via WHT of w ----
    float uh = wht32(w, lane);
    float uh0 = bcast_half(uh, 0, bbase);
    float invx2 = invx * invx;

    // Lane l holds row r = l-1 of H:
    // H[r][e] = 0.25*(uh0 - uh[r+1] - uh[e+1] + uh[(r+1)^(e+1)]) + (r==e)/x^2
    // At lane l: uh[r+1] = own uh; uh[(r+1)^(e+1)] = shfl_xor(uh, e+1).
    float A = uh0 - uh;
    float Hrow[NDIM];
#pragma unroll
    for (int e = 0; e < NDIM; ++e) {
        float ue  = bcast_half(uh, e + 1, bbase);
        float uxe = __shfl_xor(uh, e + 1);
        float h = 0.25f * ((A - ue) + uxe);
        if (l == e + 1) h += invx2;           // diagonal barrier term
        Hrow[e] = h;
    }

    // ---- forward elimination (H = L D L^T); residual = sum b'_p^2 / U_pp ----
    float res = 0.0f;
#pragma unroll
    for (int p = 0; p < NDIM; ++p) {
        float upp = bcast_half(Hrow[p], p + 1, bbase);
        float bp  = bcast_half(b, p + 1, bbase);
        float inv_upp = rcpf(upp);
        res += bp * bp * inv_upp;             // uniform within half
        // rows below the pivot (lanes l > p+1) eliminate column p
        float factor = (l > p + 1) ? Hrow[p] * inv_upp : 0.0f;
#pragma unroll
        for (int c = p + 1; c < NDIM; ++c) {
            float upc = bcast_half(Hrow[c], p + 1, bbase);
            Hrow[c] -= factor * upc;
        }
        b -= factor * bp;
    }

    if (l == 0) out[pix] = res;
}

extern "C" void kernel_launch(void* const* d_in, const int* in_sizes, int n_in,
                              void* d_out, int out_size, void* d_ws, size_t ws_size,
                              hipStream_t stream) {
    const float* xg = (const float*)d_in[0];  // time_points
    const float* kg = (const float*)d_in[1];  // pixels
    // d_in[2] = S — structure is known analytically (Sylvester S-matrix), unused
    const float* tg = (const float*)d_in[3];  // t scalar
    float* out = (float*)d_out;

    const int threads = 256;                  // 4 waves = 8 pixels per block
    const int blocks = (NPIX * 32) / threads; // 8192
    solver_kernel<<<blocks, threads, 0, stream>>>(xg, kg, tg, out);
}

// Round 2
// 150.241 us; speedup vs baseline: 1.7779x; 1.7779x over previous
//
#include <hip/hip_runtime.h>

#define NDIM 31
#define IMG 256
#define NPIX (IMG * IMG)
#define STRIDE 36   // floats per pixel staging slot: 144B = 16B-aligned, and
                    // 36*slot % 32 gives distinct bank offsets for slots 0..7

__device__ __forceinline__ float rcpf(float x) { return __builtin_amdgcn_rcpf(x); }

// broadcast lane s (0..31) within each 32-lane half of the wave
__device__ __forceinline__ float bcast_half(float v, int s, int addr_base) {
    return __int_as_float(
        __builtin_amdgcn_ds_bpermute(addr_base + (s << 2), __float_as_int(v)));
}

// 32-point Walsh-Hadamard transform across each 32-lane half
__device__ __forceinline__ float wht32(float v, int lane) {
#pragma unroll
    for (int m = 1; m < 32; m <<= 1) {
        float o = __shfl_xor(v, m);
        v = (lane & m) ? (o - v) : (v + o);
    }
    return v;
}

__global__ __launch_bounds__(256) void solver_kernel(
    const float* __restrict__ xg,   // time_points, (H,W,31,1) flat
    const float* __restrict__ kg,   // pixels
    const float* __restrict__ tg,   // scalar t
    float* __restrict__ out)        // (H,W) flat
{
    __shared__ float stg_s[8 * STRIDE];

    const int tid = blockIdx.x * 256 + threadIdx.x;
    const int pix = tid >> 5;                 // one 32-lane half-wave per pixel
    const int lane = threadIdx.x & 63;
    const int l = lane & 31;                  // element = l-1; lane0 = WHT pad
    const int bbase = (lane & 32) << 2;       // bpermute base for this half
    float* stg = &stg_s[(threadIdx.x >> 5) * STRIDE];

    const float t = tg[0];

    float x = 1.0f, k = 0.0f;
    if (l >= 1) {
        const int base = pix * NDIM + (l - 1);
        x = xg[base];
        k = kg[base];
    }

    // ---- rate = S x via WHT: rate[d] = 0.5*(xh[0] - xh[d+1]) at lane d+1 ----
    float xt = (l >= 1) ? x : 0.0f;
    float xh = wht32(xt, lane);
    float xh0 = bcast_half(xh, 0, bbase);
    float rate = 0.5f * (xh0 - xh);

    float inv_rate = rcpf(rate);
    if (l == 0) inv_rate = 0.0f;

    float v = t * (k * inv_rate - 1.0f) + inv_rate;
    float w = (t * k + 1.0f) * inv_rate * inv_rate;
    if (l == 0) { v = 0.0f; w = 0.0f; }

    // ---- J ----
    float vh = wht32(v, lane);
    float vh0 = bcast_half(vh, 0, bbase);
    float invx = rcpf(x);
    float bJ = -0.5f * (vh0 - vh) - invx;     // J_{l-1} at lane l

    // ---- H formation via WHT of w; uh broadcast via LDS b128 reads ----
    float uh = wht32(w, lane);
    stg[l] = uh;
    asm volatile("" ::: "memory");
    float4 uq[8];
#pragma unroll
    for (int j = 0; j < 8; ++j)
        uq[j] = *reinterpret_cast<float4*>(&stg[4 * j]);
    const float* uf = reinterpret_cast<const float*>(uq);  // uf[s] = uh[s]
    const float uh0 = uf[0];
    const float invx2 = invx * invx;
    const float A = uh0 - uh;

    // Augmented row: Hr[0..30] = H[r][0..30], Hr[31] = J_r  (row r = l-1)
    float Hr[32];
#pragma unroll
    for (int e = 0; e < NDIM; ++e) {
        float uxe = __shfl_xor(uh, e + 1);
        float h = 0.25f * ((A - uf[e + 1]) + uxe);
        if (l == e + 1) h += invx2;
        Hr[e] = h;
    }
    Hr[31] = bJ;
    asm volatile("" ::: "memory");

    // ---- forward elimination on augmented symmetric system ----
    // Pivot row U[p][c] = U[c][p] = lane(c+1)'s Hr[p]  (symmetry):
    // stage own Hr[p], read back slots [p+1..31] as broadcast b128 chunks.
    float res = 0.0f;
#pragma unroll
    for (int p = 0; p < NDIM; ++p) {
        stg[l] = Hr[p];
        float bp = bcast_half(Hr[31], p + 1, bbase);   // b_p (pivot row's J)
        asm volatile("" ::: "memory");
        const int cbase = (p + 1) & ~3;
        const int nch = (32 - cbase) / 4;
        float4 cq[8];
#pragma unroll
        for (int j = 0; j < nch; ++j)
            cq[j] = *reinterpret_cast<float4*>(&stg[cbase + 4 * j]);
        const float* cf = reinterpret_cast<const float*>(cq); // cf[s-cbase]=slot s

        const float upp = cf[(p + 1) - cbase];         // slot p+1 = U[p][p]
        const float inv_upp = rcpf(upp);
        res += bp * bp * inv_upp;                      // uniform within half

        const float factor = (l > p + 1) ? Hr[p] * inv_upp : 0.0f;
#pragma unroll
        for (int c = p + 1; c < NDIM; ++c)
            Hr[c] -= factor * cf[(c + 1) - cbase];     // slot c+1 = U[p][c]
        Hr[31] -= factor * bp;
        asm volatile("" ::: "memory");
    }

    if (l == 0) out[pix] = res;
}

extern "C" void kernel_launch(void* const* d_in, const int* in_sizes, int n_in,
                              void* d_out, int out_size, void* d_ws, size_t ws_size,
                              hipStream_t stream) {
    const float* xg = (const float*)d_in[0];  // time_points
    const float* kg = (const float*)d_in[1];  // pixels
    // d_in[2] = S — Sylvester S-matrix, structure known analytically, unused
    const float* tg = (const float*)d_in[3];  // t scalar
    float* out = (float*)d_out;

    const int threads = 256;                  // 4 waves = 8 pixels per block
    const int blocks = (NPIX * 32) / threads; // 8192
    solver_kernel<<<blocks, threads, 0, stream>>>(xg, kg, tg, out);
}